// Round 14
// baseline (213.459 us; speedup 1.0000x reference)
//
#include <hip/hip_runtime.h>
#include <math.h>

#define N_NODES 100000
#define NG 100
#define N_PER 1000
#define N_EDGES 3200000
#define EPG 32000
#define EPG4 8000
#define EPGP 35008
#define K_TOP 800
#define F_IN 128
#define F_MID 16
#define F_OUT 256
#define SENT 1000
#define NCH 8
#define CHN 128

typedef __attribute__((ext_vector_type(8))) short short8;
typedef __attribute__((ext_vector_type(4))) float floatx4;

__device__ __forceinline__ unsigned short f2bf(float x) {
    union { float f; unsigned int u; } c; c.f = x;
    unsigned int u = c.u;
    u = u + 0x7FFF + ((u >> 16) & 1);
    return (unsigned short)(u >> 16);
}
__device__ __forceinline__ void add4(float4& a, const float4 b) {
    a.x += b.x; a.y += b.y; a.z += b.z; a.w += b.w;
}
// swizzled feat element offset for (node s, channel-quad l): kills 8-way bank conflicts
__device__ __forceinline__ int fidx4(int s, int l) {
    return s * 16 + ((4 * (l + ((s >> 1) & 3))) & 15);
}
// order-preserving float->uint key (ascending)
__device__ __forceinline__ unsigned int fkey(float f) {
    unsigned int u = __float_as_uint(f);
    return (u & 0x80000000u) ? ~u : (u | 0x80000000u);
}

// ============ kernel 1: CSR-in-LDS blocks (1024 thr) + scalar-W GEMM1 ============
__global__ __launch_bounds__(1024) void k_front(const float* __restrict__ x,
    const float* __restrict__ W1, const int* __restrict__ ei,
    unsigned short* __restrict__ csr, int* __restrict__ crG,
    float* __restrict__ dis1G, float* __restrict__ xw1)
{
    // CSR branch LDS: 4+4+0.25+70 ~= 78KB (rank, src AND dst live in registers)
    __shared__ int cnts[N_PER];
    __shared__ int rs[N_PER];
    __shared__ int wtot[64];
    __shared__ __align__(16) unsigned short csrl[EPGP];  // whole per-graph CSR, 70KB

    int b = blockIdx.x, t = threadIdx.x;
    if (b < NG) {
        int g = b, ebase = g * EPG, nbase = g * N_PER;
        if (b == 0 && t < F_MID) xw1[(size_t)N_NODES * F_MID + t] = 0.f; // sentinel row
        const int4* dst4 = (const int4*)(ei + N_EDGES + ebase);
        const int4* src4 = (const int4*)(ei + ebase);
        if (t < N_PER) cnts[t] = 0;
        __syncthreads();
        // ---- pass 1: SINGLE edge stream. Keep rank + local src/dst (u16-packed)
        //      in registers; pass 2 then touches no global memory. Static
        //      full-unroll indexing keeps all arrays in VGPRs (not scratch).
        uint2 spk[8], dpk[8];
        unsigned rkreg[8];
#pragma unroll
        for (int j = 0; j < 8; j++) {
            int i = t + (j << 10);
            if (i < EPG4) {
                int4 s = src4[i];
                int4 d = dst4[i];
                unsigned dl0 = (unsigned)(d.x - nbase), dl1 = (unsigned)(d.y - nbase);
                unsigned dl2 = (unsigned)(d.z - nbase), dl3 = (unsigned)(d.w - nbase);
                spk[j].x = (unsigned)(s.x - nbase) | ((unsigned)(s.y - nbase) << 16);
                spk[j].y = (unsigned)(s.z - nbase) | ((unsigned)(s.w - nbase) << 16);
                dpk[j].x = dl0 | (dl1 << 16);
                dpk[j].y = dl2 | (dl3 << 16);
                unsigned r0 = (unsigned)atomicAdd(&cnts[dl0], 1);
                unsigned r1 = (unsigned)atomicAdd(&cnts[dl1], 1);
                unsigned r2 = (unsigned)atomicAdd(&cnts[dl2], 1);
                unsigned r3 = (unsigned)atomicAdd(&cnts[dl3], 1);
                rkreg[j] = r0 | (r1 << 8) | (r2 << 16) | (r3 << 24);   // deg < 256
            }
        }
        __syncthreads();
        // ---- single-wave volatile-LDS scan of c4 over 1000 nodes (2 barriers) ----
        if (t < 64) {
            volatile int* vt = wtot;
            int base = t << 4;
            int lex[16]; int run = 0;
#pragma unroll
            for (int j = 0; j < 16; j++) {
                int idx = base + j;
                int c4j = (idx < N_PER) ? ((cnts[idx] + 3) & ~3) : 0;
                lex[j] = run; run += c4j;
            }
            vt[t] = run;
#pragma unroll
            for (int d = 1; d < 64; d <<= 1) {
                int v = (t >= d) ? vt[t - d] : 0;   // lockstep: round reads precede writes
                vt[t] = vt[t] + v;
            }
            int off = vt[t] - run;                  // exclusive offset for this lane
#pragma unroll
            for (int j = 0; j < 16; j++) {
                int idx = base + j;
                if (idx < N_PER) rs[idx] = off + lex[j];
            }
        }
        __syncthreads();
        int c = (t < N_PER) ? cnts[t] : 0;
        int c4 = (c + 3) & ~3;
        if (t < N_PER) {
            int exc = rs[t];
            crG[nbase + t] = (c << 16) | exc;     // pack cnt|rs (both < 2^16)
            dis1G[nbase + t] = rsqrtf((float)c + 1.0f);
            for (int q = c; q < c4; q++) csrl[exc + q] = (unsigned short)SENT;
        }
        __syncthreads();
        // ---- pass 2: scatter into LDS CSR from REGISTERS ONLY (no global reads) ----
#pragma unroll
        for (int j = 0; j < 8; j++) {
            int i = t + (j << 10);
            if (i < EPG4) {
                unsigned rk = rkreg[j];
                unsigned dx = dpk[j].x, dy = dpk[j].y;
                unsigned sx = spk[j].x, sy = spk[j].y;
                csrl[rs[dx & 0xFFFFu] + (rk & 255u)]          = (unsigned short)(sx & 0xFFFFu);
                csrl[rs[dx >> 16]     + ((rk >> 8) & 255u)]   = (unsigned short)(sx >> 16);
                csrl[rs[dy & 0xFFFFu] + ((rk >> 16) & 255u)]  = (unsigned short)(sy & 0xFFFFu);
                csrl[rs[dy >> 16]     + (rk >> 24)]           = (unsigned short)(sy >> 16);
            }
        }
        __syncthreads();
        // ---- dump CSR to global, fully coalesced (4376 uint4) ----
        {
            const uint4* sv = (const uint4*)csrl;
            uint4* dv = (uint4*)(csr + (size_t)g * EPGP);
            for (int i = t; i < EPGP / 8; i += 1024) dv[i] = sv[i];
        }
    } else {
        // GEMM1, no LDS: one thread per node. W1 wave-uniform (scalar s_load),
        // x row = 32 sequential float4/lane, acc[16] in VGPRs. (unchanged)
        int n = (b - NG) * 1024 + t;
        if (n >= N_NODES) return;          // no barriers in this branch
        const float4* xr = (const float4*)(x + (size_t)n * F_IN);
        float4 a0 = {0,0,0,0}, a1 = a0, a2 = a0, a3 = a0;
#pragma unroll 4
        for (int kk = 0; kk < 32; kk++) {
            float4 xv = xr[kk];
#pragma unroll
            for (int r = 0; r < 4; r++) {
                const float4* wr = (const float4*)(W1 + (kk * 4 + r) * F_MID);
                float xs = (r == 0) ? xv.x : (r == 1) ? xv.y : (r == 2) ? xv.z : xv.w;
                float4 w0 = wr[0], w1 = wr[1], w2 = wr[2], w3 = wr[3];
                a0.x = fmaf(xs, w0.x, a0.x); a0.y = fmaf(xs, w0.y, a0.y);
                a0.z = fmaf(xs, w0.z, a0.z); a0.w = fmaf(xs, w0.w, a0.w);
                a1.x = fmaf(xs, w1.x, a1.x); a1.y = fmaf(xs, w1.y, a1.y);
                a1.z = fmaf(xs, w1.z, a1.z); a1.w = fmaf(xs, w1.w, a1.w);
                a2.x = fmaf(xs, w2.x, a2.x); a2.y = fmaf(xs, w2.y, a2.y);
                a2.z = fmaf(xs, w2.z, a2.z); a2.w = fmaf(xs, w2.w, a2.w);
                a3.x = fmaf(xs, w3.x, a3.x); a3.y = fmaf(xs, w3.y, a3.y);
                a3.z = fmaf(xs, w3.z, a3.z); a3.w = fmaf(xs, w3.w, a3.w);
            }
        }
        float4* op = (float4*)(xw1 + (size_t)n * F_MID);
        op[0] = a0; op[1] = a1; op[2] = a2; op[3] = a3;
    }
}

// ===== kernel 2: conv1 via LDS-staged feat (=xw1*dis1, swizzled), 800 blocks =====
__global__ __launch_bounds__(512) void k_conv1(const unsigned short* __restrict__ csr,
    const int* __restrict__ crG,
    const float* __restrict__ dis1G, const float* __restrict__ xw1,
    const float* __restrict__ b1, const float* __restrict__ w_rel,
    const float* __restrict__ w_root,
    float* __restrict__ hG, float* __restrict__ hwG, float* __restrict__ hroG)
{
    __shared__ __align__(16) float feat[(N_PER + 1) * F_MID];   // 64.06KB, 2 blk/CU
    int t = threadIdx.x, b = blockIdx.x;
    int g = b % NG, chunk = b / NG;
    int nbase = g * N_PER;
    const unsigned short* cg = csr + (size_t)g * EPGP;
    // ---- stage feat[s] = xw1[s] * dis1[s] (swizzled rows); zero sentinel ----
    {
        const float4* xsrc = (const float4*)(xw1 + (size_t)nbase * F_MID);
        for (int i = t; i < N_PER * 4; i += 512) {
            int nn = i >> 2, q = i & 3;
            float4 v = xsrc[i];
            float d = dis1G[nbase + nn];
            v.x *= d; v.y *= d; v.z *= d; v.w *= d;
            *(float4*)(feat + fidx4(nn, q)) = v;
        }
        if (t < 4) { float4 z = {0.f, 0.f, 0.f, 0.f}; *(float4*)(feat + fidx4(SENT, t)) = z; }
    }
    __syncthreads();

    int grp = t >> 2, l = t & 3;
    int n = chunk * CHN + grp;
    if (n >= N_PER) return;                 // no barriers after this point
    int cr = crG[nbase + n];
    int c4 = ((cr >> 16) + 3) & ~3;
    const unsigned short* cp = cg + (cr & 0xFFFF);
    float4 a0 = {0,0,0,0}, a1 = a0, a2 = a0, a3 = a0;
    for (int k = 0; k < c4; k += 4) {
        uint2 wv = *(const uint2*)(cp + k);
        int s0 = wv.x & 0xFFFF, s1 = wv.x >> 16, s2 = wv.y & 0xFFFF, s3 = wv.y >> 16;
        add4(a0, *(const float4*)(feat + fidx4(s0, l)));
        add4(a1, *(const float4*)(feat + fidx4(s1, l)));
        add4(a2, *(const float4*)(feat + fidx4(s2, l)));
        add4(a3, *(const float4*)(feat + fidx4(s3, l)));
    }
    add4(a0, a1); add4(a2, a3); add4(a0, a2);
    float dn = dis1G[nbase + n];
    float4 sf = *(const float4*)(feat + fidx4(n, l));
    float4 b14 = *(const float4*)(b1 + 4 * l);
    float4 hv;
    hv.x = fmaxf(fmaf(dn, a0.x + sf.x, b14.x), 0.f);
    hv.y = fmaxf(fmaf(dn, a0.y + sf.y, b14.y), 0.f);
    hv.z = fmaxf(fmaf(dn, a0.z + sf.z, b14.z), 0.f);
    hv.w = fmaxf(fmaf(dn, a0.w + sf.w, b14.w), 0.f);
    *(float4*)(hG + ((size_t)(nbase + n) << 4) + 4 * l) = hv;

    float4 wr4 = *(const float4*)(w_rel + 4 * l);
    float4 wo4 = *(const float4*)(w_root + 4 * l);
    float p1 = hv.x * wr4.x + hv.y * wr4.y + hv.z * wr4.z + hv.w * wr4.w;
    float p2 = hv.x * wo4.x + hv.y * wo4.y + hv.z * wo4.z + hv.w * wo4.w;
    p1 += __shfl_xor(p1, 1); p1 += __shfl_xor(p1, 2);
    p2 += __shfl_xor(p2, 1); p2 += __shfl_xor(p2, 2);
    if (l == 0) { hwG[nbase + n] = p1; hroG[nbase + n] = p2; }
}

// ============ kernel 3: score + top-k + mask + deg2/wsrc (per graph) ============
__global__ __launch_bounds__(1024) void k_mid(const unsigned short* __restrict__ csr,
    const int* __restrict__ crG,
    const float* __restrict__ hwG, const float* __restrict__ hroG,
    const float* __restrict__ b_rel,
    float* __restrict__ mskG, float* __restrict__ dis2G, float* __restrict__ wsrcG,
    float* __restrict__ out)
{
    __shared__ float hwl[N_PER + 1];
    __shared__ float sc[N_PER];
    __shared__ float msk[N_PER + 1];
    __shared__ int cntl[N_PER];
    __shared__ int rsl[N_PER];
    __shared__ int hist[1024];
    __shared__ int wtot[64];
    __shared__ int sh_b1, sh_r1, sh_b2, sh_r2, sh_len, sh_cntgt, sh_T;
    __shared__ float sh_thr;

    int t = threadIdx.x, g = blockIdx.x;
    int nbase = g * N_PER;
    const unsigned short* cg = csr + (size_t)g * EPGP;
    int grp = t >> 2, l = t & 3;

    if (t < N_PER) {
        int cr = crG[nbase + t];
        cntl[t] = cr >> 16; rsl[t] = cr & 0xFFFF;
        hwl[t] = hwG[nbase + t];
    }
    if (t == 0) { sh_cntgt = 0; sh_len = 0; hwl[SENT] = 0.f; }
    if (t < F_OUT) out[g * F_OUT + t] = 0.f;   // zero for conv2 atomics
    float brel = b_rel[0];
    __syncthreads();

    // ---- score: scalar gather of hw over neighbors ----
#pragma unroll
    for (int rr = 0; rr < 4; rr++) {
        int n = grp + 256 * rr;
        if (n < N_PER) {
            int c4 = (cntl[n] + 3) & ~3;
            const unsigned short* cp = cg + rsl[n];
            float sm = 0.f;
            for (int k = 0; k < c4; k += 4) {
                uint2 wv = *(const uint2*)(cp + k);
                int s = (l == 0) ? (int)(wv.x & 0xFFFF) : (l == 1) ? (int)(wv.x >> 16)
                      : (l == 2) ? (int)(wv.y & 0xFFFF) : (int)(wv.y >> 16);
                sm += hwl[s];
            }
            sm += __shfl_xor(sm, 1); sm += __shfl_xor(sm, 2);
            if (l == 0) sc[n] = tanhf(sm + hroG[nbase + n] + brel);
        }
    }
    __syncthreads();

    // ---- top-K threshold via 2-level radix histogram (exact), wave-0 scans ----
    unsigned int mykey = (t < N_PER) ? fkey(sc[t]) : 0u;
    hist[t] = 0;
    __syncthreads();
    if (t < N_PER) atomicAdd(&hist[mykey >> 22], 1);
    __syncthreads();
    int hv1 = hist[t];
    __syncthreads();
    if (t < 64) {   // wave-0 inclusive prefix of hist (volatile-LDS wave scan)
        volatile int* vt = wtot;
        int base = t << 4;
        int vv[16]; int lex[16]; int run = 0;
#pragma unroll
        for (int j = 0; j < 16; j++) { vv[j] = hist[base + j]; lex[j] = run; run += vv[j]; }
        vt[t] = run;
#pragma unroll
        for (int d = 1; d < 64; d <<= 1) { int v = (t >= d) ? vt[t - d] : 0; vt[t] = vt[t] + v; }
        int off = vt[t] - run;
        if (t == 63) sh_T = off + run;
#pragma unroll
        for (int j = 0; j < 16; j++) hist[base + j] = off + lex[j] + vv[j];
    }
    __syncthreads();
    {
        int P = hist[t], T = sh_T;
        // suffix Sb = T-P+hv >= K  &&  Snext = T-P < K
        if (P > T - K_TOP && P - hv1 <= T - K_TOP) { sh_b1 = t; sh_r1 = K_TOP - T + P; }
    }
    __syncthreads();
    int b1v = sh_b1, r1 = sh_r1;
    hist[t] = 0;
    __syncthreads();
    if (t < N_PER && (int)(mykey >> 22) == b1v) atomicAdd(&hist[(mykey >> 12) & 1023], 1);
    __syncthreads();
    int hv2 = hist[t];
    __syncthreads();
    if (t < 64) {
        volatile int* vt = wtot;
        int base = t << 4;
        int vv[16]; int lex[16]; int run = 0;
#pragma unroll
        for (int j = 0; j < 16; j++) { vv[j] = hist[base + j]; lex[j] = run; run += vv[j]; }
        vt[t] = run;
#pragma unroll
        for (int d = 1; d < 64; d <<= 1) { int v = (t >= d) ? vt[t - d] : 0; vt[t] = vt[t] + v; }
        int off = vt[t] - run;
        if (t == 63) sh_T = off + run;
#pragma unroll
        for (int j = 0; j < 16; j++) hist[base + j] = off + lex[j] + vv[j];
    }
    __syncthreads();
    {
        int P = hist[t], T = sh_T;
        if (P > T - r1 && P - hv2 <= T - r1) { sh_b2 = t; sh_r2 = r1 - T + P; }
    }
    __syncthreads();
    unsigned int pref = ((unsigned int)b1v << 10) | (unsigned int)sh_b2;
    int r2 = sh_r2;
    __syncthreads();
    if (t < N_PER && (mykey >> 12) == pref) { int p = atomicAdd(&sh_len, 1); hist[p] = (int)mykey; }
    __syncthreads();
    {
        int L = sh_len;
        if (t < L) {
            unsigned int k0 = (unsigned int)hist[t];
            int gcnt = 0, ecnt = 0;
            for (int q2 = 0; q2 < L; q2++) {
                unsigned int kq = (unsigned int)hist[q2];
                gcnt += (kq > k0); ecnt += (kq == k0);
            }
            if (gcnt < r2 && r2 <= gcnt + ecnt)
                sh_thr = __uint_as_float((k0 & 0x80000000u) ? (k0 & 0x7FFFFFFFu) : ~k0);
        }
    }
    __syncthreads();
    float thr = sh_thr;

    // ---- mask (ties: lowest index first, top_k semantics) ----
    {
        bool pred = (t < N_PER) && (sc[t] > thr);
        unsigned long long bal = __ballot(pred);
        if ((t & 63) == 0) atomicAdd(&sh_cntgt, (int)__popcll(bal));
    }
    __syncthreads();
    {
        int need = K_TOP - sh_cntgt;
        if (t < N_PER) {
            float v = sc[t];
            float mm;
            if (v > thr) mm = 1.f;
            else if (v < thr) mm = 0.f;
            else {
                int r = 0;
                for (int q2 = 0; q2 < t; q2++) if (sc[q2] == thr) r++;
                mm = (r < need) ? 1.f : 0.f;
            }
            msk[t] = mm;
        }
        if (t == 0) msk[SENT] = 0.f;
    }
    __syncthreads();

    // ---- deg2 / dis2 / wsrc (scalar mask gather) ----
#pragma unroll
    for (int rr = 0; rr < 4; rr++) {
        int n = grp + 256 * rr;
        if (n < N_PER) {
            int c4 = (cntl[n] + 3) & ~3;
            const unsigned short* cp = cg + rsl[n];
            float sm = 0.f;
            for (int k = 0; k < c4; k += 4) {
                uint2 wv = *(const uint2*)(cp + k);
                int s = (l == 0) ? (int)(wv.x & 0xFFFF) : (l == 1) ? (int)(wv.x >> 16)
                      : (l == 2) ? (int)(wv.y & 0xFFFF) : (int)(wv.y >> 16);
                sm += msk[s];
            }
            sm += __shfl_xor(sm, 1); sm += __shfl_xor(sm, 2);
            if (l == 0) {
                float d2 = msk[n] * (sm + 1.f);
                float di = (d2 > 0.f) ? rsqrtf(d2) : 0.f;
                mskG[nbase + n] = msk[n];
                dis2G[nbase + n] = di;
                wsrcG[nbase + n] = sc[n] * msk[n] * di;
            }
        }
    }
}

// ===== kernel 4: conv2 via LDS-staged feat2 (=h*wsrc, swizzled) + MFMA, 800 blocks =====
__global__ __launch_bounds__(512) void k_conv2(const unsigned short* __restrict__ csr,
    const int* __restrict__ crG,
    const float* __restrict__ hG, const float* __restrict__ wsrcG,
    const float* __restrict__ dis2G, const float* __restrict__ mskG,
    const float* __restrict__ W2, const float* __restrict__ b2,
    float* __restrict__ out)
{
    __shared__ __align__(16) float feat2[(N_PER + 1) * F_MID];  // 64.06KB
    __shared__ __align__(16) unsigned short fbf[CHN * F_MID];   // 4KB
    __shared__ __align__(16) unsigned short w2t[F_OUT * F_MID]; // 8KB
    __shared__ float mskl[CHN];
    int t = threadIdx.x, b = blockIdx.x;
    int g = b % NG, chunk = b / NG;
    int nbase = g * N_PER, n0 = chunk * CHN;
    const unsigned short* cg = csr + (size_t)g * EPGP;

    // ---- stage feat2[s] = h[s] * wsrc[s] (swizzled); zero sentinel ----
    {
        const float4* hsrc = (const float4*)(hG + (size_t)nbase * F_MID);
        for (int i = t; i < N_PER * 4; i += 512) {
            int nn = i >> 2, q = i & 3;
            float4 v = hsrc[i];
            float w = wsrcG[nbase + nn];
            v.x *= w; v.y *= w; v.z *= w; v.w *= w;
            *(float4*)(feat2 + fidx4(nn, q)) = v;
        }
        if (t < 4) { float4 z = {0.f, 0.f, 0.f, 0.f}; *(float4*)(feat2 + fidx4(SENT, t)) = z; }
    }
    for (int i = t; i < F_OUT * F_MID; i += 512) {
        int f = i >> 4, jj = i & 15;
        w2t[i] = f2bf(W2[jj * F_OUT + f]);
    }
    __syncthreads();

    int grp = t >> 2, l = t & 3;
    int n = n0 + grp;
    if (n < N_PER) {
        float di = dis2G[nbase + n];
        float4 pv = {0.f, 0.f, 0.f, 0.f};
        if (di != 0.f) {
            int cr = crG[nbase + n];
            int c4 = ((cr >> 16) + 3) & ~3;
            const unsigned short* cp = cg + (cr & 0xFFFF);
            float4 a0 = {0,0,0,0}, a1 = a0, a2 = a0, a3 = a0;
            for (int k = 0; k < c4; k += 4) {
                uint2 wv = *(const uint2*)(cp + k);
                int s0 = wv.x & 0xFFFF, s1 = wv.x >> 16, s2 = wv.y & 0xFFFF, s3 = wv.y >> 16;
                add4(a0, *(const float4*)(feat2 + fidx4(s0, l)));
                add4(a1, *(const float4*)(feat2 + fidx4(s1, l)));
                add4(a2, *(const float4*)(feat2 + fidx4(s2, l)));
                add4(a3, *(const float4*)(feat2 + fidx4(s3, l)));
            }
            add4(a0, a1); add4(a2, a3); add4(a0, a2);
            float4 sf = *(const float4*)(feat2 + fidx4(n, l));
            pv.x = di * (a0.x + sf.x);
            pv.y = di * (a0.y + sf.y);
            pv.z = di * (a0.z + sf.z);
            pv.w = di * (a0.w + sf.w);
        }
        unsigned int pk0 = (unsigned int)f2bf(pv.x) | ((unsigned int)f2bf(pv.y) << 16);
        unsigned int pk1 = (unsigned int)f2bf(pv.z) | ((unsigned int)f2bf(pv.w) << 16);
        *(unsigned int*)(fbf + grp * F_MID + 4 * l) = pk0;
        *(unsigned int*)(fbf + grp * F_MID + 4 * l + 2) = pk1;
        if (l == 0) mskl[grp] = mskG[nbase + n];
    } else {
        *(unsigned int*)(fbf + grp * F_MID + 4 * l) = 0u;
        *(unsigned int*)(fbf + grp * F_MID + 4 * l + 2) = 0u;
        if (l == 0) mskl[grp] = 0.f;
    }
    __syncthreads();

    // ---- (128x16)@(16x256) MFMA over this chunk, masked col-sums -> atomicAdd ----
    {
        int wave = t >> 6, lane = t & 63;
        int q = lane >> 4, fl = lane & 15;
        int c0 = 32 * wave + fl, c1 = c0 + 16;
        float b2f0 = b2[c0], b2f1 = b2[c1];
        short8 bfrag0 = {0,0,0,0,0,0,0,0}, bfrag1 = bfrag0;
        if (q < 2) {
            bfrag0 = *(const short8*)(w2t + c0 * F_MID + q * 8);
            bfrag1 = *(const short8*)(w2t + c1 * F_MID + q * 8);
        }
        floatx4 zero = {0.f, 0.f, 0.f, 0.f};
        float acc0 = 0.f, acc1 = 0.f;
        for (int tile = 0; tile < CHN / 16; tile++) {
            short8 afrag = {0,0,0,0,0,0,0,0};
            int na = tile * 16 + fl;
            if (q < 2)
                afrag = *(const short8*)(fbf + na * F_MID + q * 8);
            floatx4 d0 = __builtin_amdgcn_mfma_f32_16x16x32_bf16(afrag, bfrag0, zero, 0, 0, 0);
            floatx4 d1 = __builtin_amdgcn_mfma_f32_16x16x32_bf16(afrag, bfrag1, zero, 0, 0, 0);
#pragma unroll
            for (int r = 0; r < 4; r++) {
                int nd = tile * 16 + q * 4 + r;
                float m = mskl[nd];
                acc0 += m * fmaxf(d0[r] + b2f0, 0.f);
                acc1 += m * fmaxf(d1[r] + b2f1, 0.f);
            }
        }
        acc0 += __shfl_xor(acc0, 16); acc0 += __shfl_xor(acc0, 32);
        acc1 += __shfl_xor(acc1, 16); acc1 += __shfl_xor(acc1, 32);
        if (lane < 16) {
            atomicAdd(&out[g * F_OUT + c0], acc0 * (1.0f / (float)K_TOP));
            atomicAdd(&out[g * F_OUT + c1], acc1 * (1.0f / (float)K_TOP));
        }
    }
}

extern "C" void kernel_launch(void* const* d_in, const int* in_sizes, int n_in,
                              void* d_out, int out_size, void* d_ws, size_t ws_size,
                              hipStream_t stream) {
    const float* x      = (const float*)d_in[0];
    const int*   ei     = (const int*)d_in[1];
    const float* W1     = (const float*)d_in[3];
    const float* b1     = (const float*)d_in[4];
    const float* w_rel  = (const float*)d_in[5];
    const float* b_rel  = (const float*)d_in[6];
    const float* w_root = (const float*)d_in[7];
    const float* W2     = (const float*)d_in[8];
    const float* b2     = (const float*)d_in[9];
    float* out = (float*)d_out;

    char* ws = (char*)d_ws;
    size_t o = 0;
    auto nxt = [&](size_t bytes) { void* p = ws + o; o += (bytes + 255) & ~(size_t)255; return p; };
    unsigned short* csr = (unsigned short*)nxt((size_t)NG * EPGP * sizeof(unsigned short));
    int*   crG   = (int*)nxt((size_t)N_NODES * sizeof(int));
    float* dis1G = (float*)nxt((size_t)N_NODES * sizeof(float));
    float* xw1   = (float*)nxt(((size_t)N_NODES + 1) * F_MID * sizeof(float));
    float* hG    = (float*)nxt(((size_t)N_NODES + 1) * F_MID * sizeof(float));
    float* hwG   = (float*)nxt((size_t)N_NODES * sizeof(float));
    float* hroG  = (float*)nxt((size_t)N_NODES * sizeof(float));
    float* mskG  = (float*)nxt((size_t)N_NODES * sizeof(float));
    float* dis2G = (float*)nxt((size_t)N_NODES * sizeof(float));
    float* wsrcG = (float*)nxt((size_t)N_NODES * sizeof(float));

    int gemm_blocks = (N_NODES + 1023) / 1024;   // 1024 nodes per 1024-thr block
    k_front<<<NG + gemm_blocks, 1024, 0, stream>>>(x, W1, ei, csr, crG, dis1G, xw1);
    k_conv1<<<NG * NCH, 512, 0, stream>>>(csr, crG, dis1G, xw1, b1, w_rel, w_root, hG, hwG, hroG);
    k_mid<<<NG, 1024, 0, stream>>>(csr, crG, hwG, hroG, b_rel, mskG, dis2G, wsrcG, out);
    k_conv2<<<NG * NCH, 512, 0, stream>>>(csr, crG, hG, wsrcG, dis2G, mskG, W2, b2, out);
}

// Round 15
// 196.361 us; speedup vs baseline: 1.0871x; 1.0871x over previous
//
#include <hip/hip_runtime.h>
#include <math.h>

#define N_NODES 100000
#define NG 100
#define N_PER 1000
#define N_EDGES 3200000
#define EPG 32000
#define EPG4 8000
#define EPGP 35008
#define K_TOP 800
#define F_IN 128
#define F_MID 16
#define F_OUT 256
#define SENT 1000
#define NCH 8
#define CHN 128
#define WSTRIDE 20

typedef __attribute__((ext_vector_type(8))) short short8;
typedef __attribute__((ext_vector_type(4))) float floatx4;

__device__ __forceinline__ unsigned short f2bf(float x) {
    union { float f; unsigned int u; } c; c.f = x;
    unsigned int u = c.u;
    u = u + 0x7FFF + ((u >> 16) & 1);
    return (unsigned short)(u >> 16);
}
__device__ __forceinline__ void add4(float4& a, const float4 b) {
    a.x += b.x; a.y += b.y; a.z += b.z; a.w += b.w;
}
// swizzled feat element offset for (node s, channel-quad l): kills 8-way bank conflicts
__device__ __forceinline__ int fidx4(int s, int l) {
    return s * 16 + ((4 * (l + ((s >> 1) & 3))) & 15);
}
// order-preserving float->uint key (ascending)
__device__ __forceinline__ unsigned int fkey(float f) {
    unsigned int u = __float_as_uint(f);
    return (u & 0x80000000u) ? ~u : (u | 0x80000000u);
}

// ============ kernel 1: CSR-in-LDS blocks (1024 thr) + coalesced GEMM1 ============
__global__ __launch_bounds__(1024) void k_front(const float* __restrict__ x,
    const float* __restrict__ W1, const int* __restrict__ ei,
    unsigned short* __restrict__ csr, int* __restrict__ crG,
    float* __restrict__ dis1G, float* __restrict__ xw1)
{
    // CSR branch LDS: 4+4+0.25+70 ~= 78KB; GEMM branch reuses csrl as W1 stage
    __shared__ int cnts[N_PER];
    __shared__ int rs[N_PER];
    __shared__ int wtot[64];
    __shared__ __align__(16) unsigned short csrl[EPGP];  // CSR (70KB) / W1 stage (10KB)

    int b = blockIdx.x, t = threadIdx.x;
    if (b < NG) {
        int g = b, ebase = g * EPG, nbase = g * N_PER;
        if (b == 0 && t < F_MID) xw1[(size_t)N_NODES * F_MID + t] = 0.f; // sentinel row
        const int4* dst4 = (const int4*)(ei + N_EDGES + ebase);
        const int4* src4 = (const int4*)(ei + ebase);
        if (t < N_PER) cnts[t] = 0;
        __syncthreads();
        // ---- pass 1: SINGLE edge stream; rank + local src/dst in registers ----
        uint2 spk[8], dpk[8];
        unsigned rkreg[8];
#pragma unroll
        for (int j = 0; j < 8; j++) {
            int i = t + (j << 10);
            if (i < EPG4) {
                int4 s = src4[i];
                int4 d = dst4[i];
                unsigned dl0 = (unsigned)(d.x - nbase), dl1 = (unsigned)(d.y - nbase);
                unsigned dl2 = (unsigned)(d.z - nbase), dl3 = (unsigned)(d.w - nbase);
                spk[j].x = (unsigned)(s.x - nbase) | ((unsigned)(s.y - nbase) << 16);
                spk[j].y = (unsigned)(s.z - nbase) | ((unsigned)(s.w - nbase) << 16);
                dpk[j].x = dl0 | (dl1 << 16);
                dpk[j].y = dl2 | (dl3 << 16);
                unsigned r0 = (unsigned)atomicAdd(&cnts[dl0], 1);
                unsigned r1 = (unsigned)atomicAdd(&cnts[dl1], 1);
                unsigned r2 = (unsigned)atomicAdd(&cnts[dl2], 1);
                unsigned r3 = (unsigned)atomicAdd(&cnts[dl3], 1);
                rkreg[j] = r0 | (r1 << 8) | (r2 << 16) | (r3 << 24);   // deg < 256
            }
        }
        __syncthreads();
        // ---- single-wave volatile-LDS scan of c4 over 1000 nodes (2 barriers) ----
        if (t < 64) {
            volatile int* vt = wtot;
            int base = t << 4;
            int lex[16]; int run = 0;
#pragma unroll
            for (int j = 0; j < 16; j++) {
                int idx = base + j;
                int c4j = (idx < N_PER) ? ((cnts[idx] + 3) & ~3) : 0;
                lex[j] = run; run += c4j;
            }
            vt[t] = run;
#pragma unroll
            for (int d = 1; d < 64; d <<= 1) {
                int v = (t >= d) ? vt[t - d] : 0;   // lockstep
                vt[t] = vt[t] + v;
            }
            int off = vt[t] - run;
#pragma unroll
            for (int j = 0; j < 16; j++) {
                int idx = base + j;
                if (idx < N_PER) rs[idx] = off + lex[j];
            }
        }
        __syncthreads();
        int c = (t < N_PER) ? cnts[t] : 0;
        int c4 = (c + 3) & ~3;
        if (t < N_PER) {
            int exc = rs[t];
            crG[nbase + t] = (c << 16) | exc;     // pack cnt|rs (both < 2^16)
            dis1G[nbase + t] = rsqrtf((float)c + 1.0f);
            for (int q = c; q < c4; q++) csrl[exc + q] = (unsigned short)SENT;
        }
        __syncthreads();
        // ---- pass 2: scatter into LDS CSR from registers only ----
#pragma unroll
        for (int j = 0; j < 8; j++) {
            int i = t + (j << 10);
            if (i < EPG4) {
                unsigned rk = rkreg[j];
                unsigned dx = dpk[j].x, dy = dpk[j].y;
                unsigned sx = spk[j].x, sy = spk[j].y;
                csrl[rs[dx & 0xFFFFu] + (rk & 255u)]          = (unsigned short)(sx & 0xFFFFu);
                csrl[rs[dx >> 16]     + ((rk >> 8) & 255u)]   = (unsigned short)(sx >> 16);
                csrl[rs[dy & 0xFFFFu] + ((rk >> 16) & 255u)]  = (unsigned short)(sy & 0xFFFFu);
                csrl[rs[dy >> 16]     + (rk >> 24)]           = (unsigned short)(sy >> 16);
            }
        }
        __syncthreads();
        // ---- dump CSR to global, fully coalesced (4376 uint4) ----
        {
            const uint4* sv = (const uint4*)csrl;
            uint4* dv = (uint4*)(csr + (size_t)g * EPGP);
            for (int i = t; i < EPGP / 8; i += 1024) dv[i] = sv[i];
        }
    } else {
        // GEMM1 v2: 4 lanes/node, k-interleaved COALESCED x reads (lanes 16B-
        // consecutive -> 16 lines/instr vs 64), W1 staged in LDS (row stride 20
        // floats: 16B-aligned, broadcast across node-groups, 2-way across lanes).
        float* w1s = (float*)csrl;            // reuse CSR LDS (disjoint branch)
        for (int i = t; i < F_IN * F_MID; i += 1024) {
            int row = i >> 4, col = i & 15;
            w1s[row * WSTRIDE + col] = W1[i];
        }
        __syncthreads();                       // uniform: whole block in this branch
        int nl = t >> 2, l = t & 3;
        int n = (b - NG) * 256 + nl;
        if (n >= N_NODES) return;              // no barriers after this point
        const float* xb = x + (size_t)n * F_IN + l * 4;
        float4 a0 = {0,0,0,0}, a1 = a0, a2 = a0, a3 = a0;
#pragma unroll
        for (int kk = 0; kk < 8; kk++) {
            float4 xv = *(const float4*)(xb + kk * 16);   // lanes l=0..3 contiguous 64B
#pragma unroll
            for (int j = 0; j < 4; j++) {
                int k = kk * 16 + l * 4 + j;
                float xs = (j == 0) ? xv.x : (j == 1) ? xv.y : (j == 2) ? xv.z : xv.w;
                const float4* wr = (const float4*)(w1s + k * WSTRIDE);
                float4 w0 = wr[0], w1 = wr[1], w2 = wr[2], w3 = wr[3];
                a0.x = fmaf(xs, w0.x, a0.x); a0.y = fmaf(xs, w0.y, a0.y);
                a0.z = fmaf(xs, w0.z, a0.z); a0.w = fmaf(xs, w0.w, a0.w);
                a1.x = fmaf(xs, w1.x, a1.x); a1.y = fmaf(xs, w1.y, a1.y);
                a1.z = fmaf(xs, w1.z, a1.z); a1.w = fmaf(xs, w1.w, a1.w);
                a2.x = fmaf(xs, w2.x, a2.x); a2.y = fmaf(xs, w2.y, a2.y);
                a2.z = fmaf(xs, w2.z, a2.z); a2.w = fmaf(xs, w2.w, a2.w);
                a3.x = fmaf(xs, w3.x, a3.x); a3.y = fmaf(xs, w3.y, a3.y);
                a3.z = fmaf(xs, w3.z, a3.z); a3.w = fmaf(xs, w3.w, a3.w);
            }
        }
        // reduce k-partials across the 4 lanes of this node (proven shfl_xor idiom)
#define KRED(c) c += __shfl_xor(c, 1); c += __shfl_xor(c, 2);
        KRED(a0.x) KRED(a0.y) KRED(a0.z) KRED(a0.w)
        KRED(a1.x) KRED(a1.y) KRED(a1.z) KRED(a1.w)
        KRED(a2.x) KRED(a2.y) KRED(a2.z) KRED(a2.w)
        KRED(a3.x) KRED(a3.y) KRED(a3.z) KRED(a3.w)
#undef KRED
        if (l == 0) {
            float4* op = (float4*)(xw1 + (size_t)n * F_MID);
            op[0] = a0; op[1] = a1; op[2] = a2; op[3] = a3;
        }
    }
}

// ===== kernel 2: conv1 via LDS-staged feat (=xw1*dis1, swizzled), 800 blocks =====
__global__ __launch_bounds__(512) void k_conv1(const unsigned short* __restrict__ csr,
    const int* __restrict__ crG,
    const float* __restrict__ dis1G, const float* __restrict__ xw1,
    const float* __restrict__ b1, const float* __restrict__ w_rel,
    const float* __restrict__ w_root,
    float* __restrict__ hG, float* __restrict__ hwG, float* __restrict__ hroG)
{
    __shared__ __align__(16) float feat[(N_PER + 1) * F_MID];   // 64.06KB, 2 blk/CU
    int t = threadIdx.x, b = blockIdx.x;
    int g = b % NG, chunk = b / NG;
    int nbase = g * N_PER;
    const unsigned short* cg = csr + (size_t)g * EPGP;
    // ---- stage feat[s] = xw1[s] * dis1[s] (swizzled rows); zero sentinel ----
    {
        const float4* xsrc = (const float4*)(xw1 + (size_t)nbase * F_MID);
        for (int i = t; i < N_PER * 4; i += 512) {
            int nn = i >> 2, q = i & 3;
            float4 v = xsrc[i];
            float d = dis1G[nbase + nn];
            v.x *= d; v.y *= d; v.z *= d; v.w *= d;
            *(float4*)(feat + fidx4(nn, q)) = v;
        }
        if (t < 4) { float4 z = {0.f, 0.f, 0.f, 0.f}; *(float4*)(feat + fidx4(SENT, t)) = z; }
    }
    __syncthreads();

    int grp = t >> 2, l = t & 3;
    int n = chunk * CHN + grp;
    if (n >= N_PER) return;                 // no barriers after this point
    int cr = crG[nbase + n];
    int c4 = ((cr >> 16) + 3) & ~3;
    const unsigned short* cp = cg + (cr & 0xFFFF);
    float4 a0 = {0,0,0,0}, a1 = a0, a2 = a0, a3 = a0;
    for (int k = 0; k < c4; k += 4) {
        uint2 wv = *(const uint2*)(cp + k);
        int s0 = wv.x & 0xFFFF, s1 = wv.x >> 16, s2 = wv.y & 0xFFFF, s3 = wv.y >> 16;
        add4(a0, *(const float4*)(feat + fidx4(s0, l)));
        add4(a1, *(const float4*)(feat + fidx4(s1, l)));
        add4(a2, *(const float4*)(feat + fidx4(s2, l)));
        add4(a3, *(const float4*)(feat + fidx4(s3, l)));
    }
    add4(a0, a1); add4(a2, a3); add4(a0, a2);
    float dn = dis1G[nbase + n];
    float4 sf = *(const float4*)(feat + fidx4(n, l));
    float4 b14 = *(const float4*)(b1 + 4 * l);
    float4 hv;
    hv.x = fmaxf(fmaf(dn, a0.x + sf.x, b14.x), 0.f);
    hv.y = fmaxf(fmaf(dn, a0.y + sf.y, b14.y), 0.f);
    hv.z = fmaxf(fmaf(dn, a0.z + sf.z, b14.z), 0.f);
    hv.w = fmaxf(fmaf(dn, a0.w + sf.w, b14.w), 0.f);
    *(float4*)(hG + ((size_t)(nbase + n) << 4) + 4 * l) = hv;

    float4 wr4 = *(const float4*)(w_rel + 4 * l);
    float4 wo4 = *(const float4*)(w_root + 4 * l);
    float p1 = hv.x * wr4.x + hv.y * wr4.y + hv.z * wr4.z + hv.w * wr4.w;
    float p2 = hv.x * wo4.x + hv.y * wo4.y + hv.z * wo4.z + hv.w * wo4.w;
    p1 += __shfl_xor(p1, 1); p1 += __shfl_xor(p1, 2);
    p2 += __shfl_xor(p2, 1); p2 += __shfl_xor(p2, 2);
    if (l == 0) { hwG[nbase + n] = p1; hroG[nbase + n] = p2; }
}

// ============ kernel 3: score + top-k + mask + deg2/wsrc (per graph) ============
__global__ __launch_bounds__(1024) void k_mid(const unsigned short* __restrict__ csr,
    const int* __restrict__ crG,
    const float* __restrict__ hwG, const float* __restrict__ hroG,
    const float* __restrict__ b_rel,
    float* __restrict__ mskG, float* __restrict__ dis2G, float* __restrict__ wsrcG,
    float* __restrict__ out)
{
    __shared__ float hwl[N_PER + 1];
    __shared__ float sc[N_PER];
    __shared__ float msk[N_PER + 1];
    __shared__ int cntl[N_PER];
    __shared__ int rsl[N_PER];
    __shared__ int hist[1024];
    __shared__ int wtot[64];
    __shared__ int sh_b1, sh_r1, sh_b2, sh_r2, sh_len, sh_cntgt, sh_T;
    __shared__ float sh_thr;

    int t = threadIdx.x, g = blockIdx.x;
    int nbase = g * N_PER;
    const unsigned short* cg = csr + (size_t)g * EPGP;
    int grp = t >> 2, l = t & 3;

    if (t < N_PER) {
        int cr = crG[nbase + t];
        cntl[t] = cr >> 16; rsl[t] = cr & 0xFFFF;
        hwl[t] = hwG[nbase + t];
    }
    if (t == 0) { sh_cntgt = 0; sh_len = 0; hwl[SENT] = 0.f; }
    if (t < F_OUT) out[g * F_OUT + t] = 0.f;   // zero for conv2 atomics
    float brel = b_rel[0];
    __syncthreads();

    // ---- score: scalar gather of hw over neighbors ----
#pragma unroll
    for (int rr = 0; rr < 4; rr++) {
        int n = grp + 256 * rr;
        if (n < N_PER) {
            int c4 = (cntl[n] + 3) & ~3;
            const unsigned short* cp = cg + rsl[n];
            float sm = 0.f;
            for (int k = 0; k < c4; k += 4) {
                uint2 wv = *(const uint2*)(cp + k);
                int s = (l == 0) ? (int)(wv.x & 0xFFFF) : (l == 1) ? (int)(wv.x >> 16)
                      : (l == 2) ? (int)(wv.y & 0xFFFF) : (int)(wv.y >> 16);
                sm += hwl[s];
            }
            sm += __shfl_xor(sm, 1); sm += __shfl_xor(sm, 2);
            if (l == 0) sc[n] = tanhf(sm + hroG[nbase + n] + brel);
        }
    }
    __syncthreads();

    // ---- top-K threshold via 2-level radix histogram (exact), wave-0 scans ----
    unsigned int mykey = (t < N_PER) ? fkey(sc[t]) : 0u;
    hist[t] = 0;
    __syncthreads();
    if (t < N_PER) atomicAdd(&hist[mykey >> 22], 1);
    __syncthreads();
    int hv1 = hist[t];
    __syncthreads();
    if (t < 64) {   // wave-0 inclusive prefix of hist (volatile-LDS wave scan)
        volatile int* vt = wtot;
        int base = t << 4;
        int vv[16]; int lex[16]; int run = 0;
#pragma unroll
        for (int j = 0; j < 16; j++) { vv[j] = hist[base + j]; lex[j] = run; run += vv[j]; }
        vt[t] = run;
#pragma unroll
        for (int d = 1; d < 64; d <<= 1) { int v = (t >= d) ? vt[t - d] : 0; vt[t] = vt[t] + v; }
        int off = vt[t] - run;
        if (t == 63) sh_T = off + run;
#pragma unroll
        for (int j = 0; j < 16; j++) hist[base + j] = off + lex[j] + vv[j];
    }
    __syncthreads();
    {
        int P = hist[t], T = sh_T;
        // suffix Sb = T-P+hv >= K  &&  Snext = T-P < K
        if (P > T - K_TOP && P - hv1 <= T - K_TOP) { sh_b1 = t; sh_r1 = K_TOP - T + P; }
    }
    __syncthreads();
    int b1v = sh_b1, r1 = sh_r1;
    hist[t] = 0;
    __syncthreads();
    if (t < N_PER && (int)(mykey >> 22) == b1v) atomicAdd(&hist[(mykey >> 12) & 1023], 1);
    __syncthreads();
    int hv2 = hist[t];
    __syncthreads();
    if (t < 64) {
        volatile int* vt = wtot;
        int base = t << 4;
        int vv[16]; int lex[16]; int run = 0;
#pragma unroll
        for (int j = 0; j < 16; j++) { vv[j] = hist[base + j]; lex[j] = run; run += vv[j]; }
        vt[t] = run;
#pragma unroll
        for (int d = 1; d < 64; d <<= 1) { int v = (t >= d) ? vt[t - d] : 0; vt[t] = vt[t] + v; }
        int off = vt[t] - run;
        if (t == 63) sh_T = off + run;
#pragma unroll
        for (int j = 0; j < 16; j++) hist[base + j] = off + lex[j] + vv[j];
    }
    __syncthreads();
    {
        int P = hist[t], T = sh_T;
        if (P > T - r1 && P - hv2 <= T - r1) { sh_b2 = t; sh_r2 = r1 - T + P; }
    }
    __syncthreads();
    unsigned int pref = ((unsigned int)b1v << 10) | (unsigned int)sh_b2;
    int r2 = sh_r2;
    __syncthreads();
    if (t < N_PER && (mykey >> 12) == pref) { int p = atomicAdd(&sh_len, 1); hist[p] = (int)mykey; }
    __syncthreads();
    {
        int L = sh_len;
        if (t < L) {
            unsigned int k0 = (unsigned int)hist[t];
            int gcnt = 0, ecnt = 0;
            for (int q2 = 0; q2 < L; q2++) {
                unsigned int kq = (unsigned int)hist[q2];
                gcnt += (kq > k0); ecnt += (kq == k0);
            }
            if (gcnt < r2 && r2 <= gcnt + ecnt)
                sh_thr = __uint_as_float((k0 & 0x80000000u) ? (k0 & 0x7FFFFFFFu) : ~k0);
        }
    }
    __syncthreads();
    float thr = sh_thr;

    // ---- mask (ties: lowest index first, top_k semantics) ----
    {
        bool pred = (t < N_PER) && (sc[t] > thr);
        unsigned long long bal = __ballot(pred);
        if ((t & 63) == 0) atomicAdd(&sh_cntgt, (int)__popcll(bal));
    }
    __syncthreads();
    {
        int need = K_TOP - sh_cntgt;
        if (t < N_PER) {
            float v = sc[t];
            float mm;
            if (v > thr) mm = 1.f;
            else if (v < thr) mm = 0.f;
            else {
                int r = 0;
                for (int q2 = 0; q2 < t; q2++) if (sc[q2] == thr) r++;
                mm = (r < need) ? 1.f : 0.f;
            }
            msk[t] = mm;
        }
        if (t == 0) msk[SENT] = 0.f;
    }
    __syncthreads();

    // ---- deg2 / dis2 / wsrc (scalar mask gather) ----
#pragma unroll
    for (int rr = 0; rr < 4; rr++) {
        int n = grp + 256 * rr;
        if (n < N_PER) {
            int c4 = (cntl[n] + 3) & ~3;
            const unsigned short* cp = cg + rsl[n];
            float sm = 0.f;
            for (int k = 0; k < c4; k += 4) {
                uint2 wv = *(const uint2*)(cp + k);
                int s = (l == 0) ? (int)(wv.x & 0xFFFF) : (l == 1) ? (int)(wv.x >> 16)
                      : (l == 2) ? (int)(wv.y & 0xFFFF) : (int)(wv.y >> 16);
                sm += msk[s];
            }
            sm += __shfl_xor(sm, 1); sm += __shfl_xor(sm, 2);
            if (l == 0) {
                float d2 = msk[n] * (sm + 1.f);
                float di = (d2 > 0.f) ? rsqrtf(d2) : 0.f;
                mskG[nbase + n] = msk[n];
                dis2G[nbase + n] = di;
                wsrcG[nbase + n] = sc[n] * msk[n] * di;
            }
        }
    }
}

// ===== kernel 4: conv2 via LDS-staged feat2 (=h*wsrc, swizzled) + MFMA, 800 blocks =====
__global__ __launch_bounds__(512) void k_conv2(const unsigned short* __restrict__ csr,
    const int* __restrict__ crG,
    const float* __restrict__ hG, const float* __restrict__ wsrcG,
    const float* __restrict__ dis2G, const float* __restrict__ mskG,
    const float* __restrict__ W2, const float* __restrict__ b2,
    float* __restrict__ out)
{
    __shared__ __align__(16) float feat2[(N_PER + 1) * F_MID];  // 64.06KB
    __shared__ __align__(16) unsigned short fbf[CHN * F_MID];   // 4KB
    __shared__ __align__(16) unsigned short w2t[F_OUT * F_MID]; // 8KB
    __shared__ float mskl[CHN];
    int t = threadIdx.x, b = blockIdx.x;
    int g = b % NG, chunk = b / NG;
    int nbase = g * N_PER, n0 = chunk * CHN;
    const unsigned short* cg = csr + (size_t)g * EPGP;

    // ---- stage feat2[s] = h[s] * wsrc[s] (swizzled); zero sentinel ----
    {
        const float4* hsrc = (const float4*)(hG + (size_t)nbase * F_MID);
        for (int i = t; i < N_PER * 4; i += 512) {
            int nn = i >> 2, q = i & 3;
            float4 v = hsrc[i];
            float w = wsrcG[nbase + nn];
            v.x *= w; v.y *= w; v.z *= w; v.w *= w;
            *(float4*)(feat2 + fidx4(nn, q)) = v;
        }
        if (t < 4) { float4 z = {0.f, 0.f, 0.f, 0.f}; *(float4*)(feat2 + fidx4(SENT, t)) = z; }
    }
    for (int i = t; i < F_OUT * F_MID; i += 512) {
        int f = i >> 4, jj = i & 15;
        w2t[i] = f2bf(W2[jj * F_OUT + f]);
    }
    __syncthreads();

    int grp = t >> 2, l = t & 3;
    int n = n0 + grp;
    if (n < N_PER) {
        float di = dis2G[nbase + n];
        float4 pv = {0.f, 0.f, 0.f, 0.f};
        if (di != 0.f) {
            int cr = crG[nbase + n];
            int c4 = ((cr >> 16) + 3) & ~3;
            const unsigned short* cp = cg + (cr & 0xFFFF);
            float4 a0 = {0,0,0,0}, a1 = a0, a2 = a0, a3 = a0;
            for (int k = 0; k < c4; k += 4) {
                uint2 wv = *(const uint2*)(cp + k);
                int s0 = wv.x & 0xFFFF, s1 = wv.x >> 16, s2 = wv.y & 0xFFFF, s3 = wv.y >> 16;
                add4(a0, *(const float4*)(feat2 + fidx4(s0, l)));
                add4(a1, *(const float4*)(feat2 + fidx4(s1, l)));
                add4(a2, *(const float4*)(feat2 + fidx4(s2, l)));
                add4(a3, *(const float4*)(feat2 + fidx4(s3, l)));
            }
            add4(a0, a1); add4(a2, a3); add4(a0, a2);
            float4 sf = *(const float4*)(feat2 + fidx4(n, l));
            pv.x = di * (a0.x + sf.x);
            pv.y = di * (a0.y + sf.y);
            pv.z = di * (a0.z + sf.z);
            pv.w = di * (a0.w + sf.w);
        }
        unsigned int pk0 = (unsigned int)f2bf(pv.x) | ((unsigned int)f2bf(pv.y) << 16);
        unsigned int pk1 = (unsigned int)f2bf(pv.z) | ((unsigned int)f2bf(pv.w) << 16);
        *(unsigned int*)(fbf + grp * F_MID + 4 * l) = pk0;
        *(unsigned int*)(fbf + grp * F_MID + 4 * l + 2) = pk1;
        if (l == 0) mskl[grp] = mskG[nbase + n];
    } else {
        *(unsigned int*)(fbf + grp * F_MID + 4 * l) = 0u;
        *(unsigned int*)(fbf + grp * F_MID + 4 * l + 2) = 0u;
        if (l == 0) mskl[grp] = 0.f;
    }
    __syncthreads();

    // ---- (128x16)@(16x256) MFMA over this chunk, masked col-sums -> atomicAdd ----
    {
        int wave = t >> 6, lane = t & 63;
        int q = lane >> 4, fl = lane & 15;
        int c0 = 32 * wave + fl, c1 = c0 + 16;
        float b2f0 = b2[c0], b2f1 = b2[c1];
        short8 bfrag0 = {0,0,0,0,0,0,0,0}, bfrag1 = bfrag0;
        if (q < 2) {
            bfrag0 = *(const short8*)(w2t + c0 * F_MID + q * 8);
            bfrag1 = *(const short8*)(w2t + c1 * F_MID + q * 8);
        }
        floatx4 zero = {0.f, 0.f, 0.f, 0.f};
        float acc0 = 0.f, acc1 = 0.f;
        for (int tile = 0; tile < CHN / 16; tile++) {
            short8 afrag = {0,0,0,0,0,0,0,0};
            int na = tile * 16 + fl;
            if (q < 2)
                afrag = *(const short8*)(fbf + na * F_MID + q * 8);
            floatx4 d0 = __builtin_amdgcn_mfma_f32_16x16x32_bf16(afrag, bfrag0, zero, 0, 0, 0);
            floatx4 d1 = __builtin_amdgcn_mfma_f32_16x16x32_bf16(afrag, bfrag1, zero, 0, 0, 0);
#pragma unroll
            for (int r = 0; r < 4; r++) {
                int nd = tile * 16 + q * 4 + r;
                float m = mskl[nd];
                acc0 += m * fmaxf(d0[r] + b2f0, 0.f);
                acc1 += m * fmaxf(d1[r] + b2f1, 0.f);
            }
        }
        acc0 += __shfl_xor(acc0, 16); acc0 += __shfl_xor(acc0, 32);
        acc1 += __shfl_xor(acc1, 16); acc1 += __shfl_xor(acc1, 32);
        if (lane < 16) {
            atomicAdd(&out[g * F_OUT + c0], acc0 * (1.0f / (float)K_TOP));
            atomicAdd(&out[g * F_OUT + c1], acc1 * (1.0f / (float)K_TOP));
        }
    }
}

extern "C" void kernel_launch(void* const* d_in, const int* in_sizes, int n_in,
                              void* d_out, int out_size, void* d_ws, size_t ws_size,
                              hipStream_t stream) {
    const float* x      = (const float*)d_in[0];
    const int*   ei     = (const int*)d_in[1];
    const float* W1     = (const float*)d_in[3];
    const float* b1     = (const float*)d_in[4];
    const float* w_rel  = (const float*)d_in[5];
    const float* b_rel  = (const float*)d_in[6];
    const float* w_root = (const float*)d_in[7];
    const float* W2     = (const float*)d_in[8];
    const float* b2     = (const float*)d_in[9];
    float* out = (float*)d_out;

    char* ws = (char*)d_ws;
    size_t o = 0;
    auto nxt = [&](size_t bytes) { void* p = ws + o; o += (bytes + 255) & ~(size_t)255; return p; };
    unsigned short* csr = (unsigned short*)nxt((size_t)NG * EPGP * sizeof(unsigned short));
    int*   crG   = (int*)nxt((size_t)N_NODES * sizeof(int));
    float* dis1G = (float*)nxt((size_t)N_NODES * sizeof(float));
    float* xw1   = (float*)nxt(((size_t)N_NODES + 1) * F_MID * sizeof(float));
    float* hG    = (float*)nxt(((size_t)N_NODES + 1) * F_MID * sizeof(float));
    float* hwG   = (float*)nxt((size_t)N_NODES * sizeof(float));
    float* hroG  = (float*)nxt((size_t)N_NODES * sizeof(float));
    float* mskG  = (float*)nxt((size_t)N_NODES * sizeof(float));
    float* dis2G = (float*)nxt((size_t)N_NODES * sizeof(float));
    float* wsrcG = (float*)nxt((size_t)N_NODES * sizeof(float));

    int gemm_blocks = (N_NODES + 255) / 256;   // 256 nodes per 1024-thr block
    k_front<<<NG + gemm_blocks, 1024, 0, stream>>>(x, W1, ei, csr, crG, dis1G, xw1);
    k_conv1<<<NG * NCH, 512, 0, stream>>>(csr, crG, dis1G, xw1, b1, w_rel, w_root, hG, hwG, hroG);
    k_mid<<<NG, 1024, 0, stream>>>(csr, crG, hwG, hroG, b_rel, mskG, dis2G, wsrcG, out);
    k_conv2<<<NG * NCH, 512, 0, stream>>>(csr, crG, hG, wsrcG, dis2G, mskG, W2, b2, out);
}